// Round 6
// baseline (326.846 us; speedup 1.0000x reference)
//
#include <hip/hip_runtime.h>

#define B 8
#define N 8192
#define M 2048
#define NITER 4
#define BASE_ALPHA 0.1f

#define NTHR 1024              // 16 waves (4 waves/SIMD)
#define NPT 32                 // point-lanes per split
#define NSPLIT 32              // j-splits per block
#define JS (M / NSPLIT)        // 64 y's per split
#define PT 8                   // points per thread
#define PPB (NPT * PT)         // 256 points per block
#define NBLK (B * N / PPB)     // 256 blocks = 1/CU (unconditionally co-resident)
#define BPB (NBLK / B)         // 32 blocks per batch
#define CNT_TARGET (4 * BPB)   // 4 owner waves per block arrive independently

// ws: maxv uint[NITER*B] @0, cnt uint[NITER*B] @128 — 256 B, memsetAsync(0) per call.

__device__ __forceinline__ unsigned int ord32(float t) {
    unsigned int u = __float_as_uint(t);
    return u ^ ((unsigned int)((int)u >> 31) | 0x80000000u);   // float order -> uint order
}
__device__ __forceinline__ float dec32(unsigned int h) {
    return __uint_as_float((h & 0x80000000u) ? (h ^ 0x80000000u) : ~h);
}

__global__ __launch_bounds__(NTHR, 4) void refine_all(const float* __restrict__ pred,
                                                      const float* __restrict__ partial,
                                                      unsigned int* __restrict__ maxv,
                                                      unsigned int* __restrict__ cnt,
                                                      float* __restrict__ out) {
    __shared__ float4 tile[M + 2];                 // {-2y0,-2y1,-2y2,|y|^2}
    __shared__ unsigned long long lkeys[16][PPB];  // 32 KB: per-wave (min_t, split) keys
    __shared__ float4 lpos[PPB];                   // {x,y,z,|r|^2}
    __shared__ float mxbuf;
    __shared__ unsigned int flag;

    const int tid = threadIdx.x;
    const int b = blockIdx.x >> 5;                 // 32 blocks per batch
    const int gp0 = b * N + (blockIdx.x & 31) * PPB;

    // Build y-tile once. (-2y)*x products are bit-equal to (-2x)*y of the ref path.
    const float* pa = partial + b * M * 3;
    for (int i = tid; i < M; i += NTHR) {
        float y0 = pa[i * 3 + 0], y1 = pa[i * 3 + 1], y2 = pa[i * 3 + 2];
        tile[i] = make_float4(-2.0f * y0, -2.0f * y1, -2.0f * y2,
                              y0 * y0 + y1 * y1 + y2 * y2);
    }
    if (tid == 0) flag = 0u;
    if (tid < PPB) {
        const float* pp = pred + (unsigned long long)(gp0 + tid) * 3;
        float x = pp[0], y = pp[1], z = pp[2];
        lpos[tid] = make_float4(x, y, z, x * x + y * y + z * z);
    }
    __syncthreads();

    const int split = tid >> 5;                    // 0..31 (uniform per half-wave)
    const int pt = tid & 31;
    const int wave = tid >> 6;                     // 0..15
    const float4* __restrict__ qs = tile + split * JS;

    for (int iter = 0; iter < NITER; ++iter) {
        // ---- pass 1: per-split MIN VALUE only (3.5 VALU/pair) ----
        float x0[PT], x1[PT], x2[PT];
        #pragma unroll
        for (int k = 0; k < PT; ++k) {
            float4 r = lpos[pt + k * NPT];
            x0[k] = r.x; x1[k] = r.y; x2[k] = r.z;
        }
        float vb[PT];
        #pragma unroll
        for (int k = 0; k < PT; ++k) vb[k] = 3.402823466e+38f;

        #pragma unroll 4
        for (int j = 0; j < JS; j += 2) {
            float4 q0 = qs[j];
            float4 q1 = qs[j + 1];
            #pragma unroll
            for (int k = 0; k < PT; ++k) {
                float t0 = fmaf(x0[k], q0.x, fmaf(x1[k], q0.y, fmaf(x2[k], q0.z, q0.w)));
                float t1 = fmaf(x0[k], q1.x, fmaf(x1[k], q1.y, fmaf(x2[k], q1.z, q1.w)));
                vb[k] = fminf(fminf(t0, t1), vb[k]);   // v_min3_f32
            }
        }

        // ---- merge (value, split) across the wave's two splits, write per-wave row ----
        #pragma unroll
        for (int k = 0; k < PT; ++k) {
            unsigned int hi = ord32(vb[k]);
            unsigned int lo = (unsigned int)split;
            unsigned int ohi = __shfl_xor(hi, 32), olo = __shfl_xor(lo, 32);
            if (ohi < hi || (ohi == hi && olo < lo)) { hi = ohi; lo = olo; }  // lex min
            if ((tid & 32) == 0)
                lkeys[wave][pt + k * NPT] = (((unsigned long long)hi) << 32) | lo;
        }
        __syncthreads();                            // sync A: lkeys ready

        // ---- owners (tid<256): reduce, barrier-arrive, pass-2 re-scan, update ----
        if (tid < PPB) {
            unsigned long long best = lkeys[0][tid];
            #pragma unroll
            for (int r = 1; r < 16; ++r) {
                unsigned long long c = lkeys[r][tid];
                if (c < best) best = c;
            }
            const int bsplit = (int)(unsigned int)(best & 0xFFFFFFFFull);
            const float tstar = dec32((unsigned int)(best >> 32));
            const float4 f4 = lpos[tid];
            const float md = sqrtf(fmaxf(f4.w + tstar, 0.0f));

            // arrive at per-batch barrier (4 waves/block independently)
            float wm = md;
            for (int o = 32; o > 0; o >>= 1) wm = fmaxf(wm, __shfl_down(wm, o));
            if ((tid & 63) == 0) {
                __hip_atomic_fetch_max(&maxv[iter * B + b], __float_as_uint(wm),
                                       __ATOMIC_SEQ_CST, __HIP_MEMORY_SCOPE_AGENT);
                __hip_atomic_fetch_add(&cnt[iter * B + b], 1u,
                                       __ATOMIC_SEQ_CST, __HIP_MEMORY_SCOPE_AGENT);
            }

            // pass 2 (overlaps the cross-block barrier latency): exact first-argmin
            // within the winning split — bit-identical fmaf chain to pass 1.
            const float4* __restrict__ q2 = tile + bsplit * JS;
            float bt = 3.402823466e+38f; int bj = 0;
            for (int j = 0; j < JS; ++j) {
                float4 q = q2[j];
                float t = fmaf(f4.x, q.x, fmaf(f4.y, q.y, fmaf(f4.z, q.z, q.w)));
                if (t < bt) { bt = t; bj = j; }     // strict < keeps earliest j
            }
            const float4 nr = tile[bsplit * JS + bj];

            // finish barrier: tid0 spins, broadcasts via LDS flag
            if (tid == 0) {
                unsigned int* cv = &cnt[iter * B + b];
                while (__hip_atomic_load(cv, __ATOMIC_ACQUIRE, __HIP_MEMORY_SCOPE_AGENT)
                       < CNT_TARGET)
                    __builtin_amdgcn_s_sleep(1);
                unsigned int mu = __hip_atomic_load(&maxv[iter * B + b],
                                                    __ATOMIC_ACQUIRE, __HIP_MEMORY_SCOPE_AGENT);
                mxbuf = __uint_as_float(mu);
                __hip_atomic_store(&flag, (unsigned int)(iter + 1),
                                   __ATOMIC_RELEASE, __HIP_MEMORY_SCOPE_WORKGROUP);
            }
            if (wave != 0) {
                while (__hip_atomic_load(&flag, __ATOMIC_ACQUIRE,
                                         __HIP_MEMORY_SCOPE_WORKGROUP) < (unsigned int)(iter + 1))
                    __builtin_amdgcn_s_sleep(1);
            }
            const float mx = mxbuf;                 // wave0: same-wave DS order; others: after acquire

            const float inv = 1.0f / (mx + 1e-6f);
            const float alpha = BASE_ALPHA * (2.0f - md * inv);
            const float ny0 = -0.5f * nr.x, ny1 = -0.5f * nr.y, ny2 = -0.5f * nr.z;
            const float rx = fmaf(alpha, ny0 - f4.x, f4.x);
            const float ry = fmaf(alpha, ny1 - f4.y, f4.y);
            const float rz = fmaf(alpha, ny2 - f4.z, f4.z);
            if (iter == NITER - 1) {
                float* po = out + (unsigned long long)(gp0 + tid) * 3;
                po[0] = rx; po[1] = ry; po[2] = rz;
            } else {
                lpos[tid] = make_float4(rx, ry, rz, rx * rx + ry * ry + rz * rz);
            }
        }
        __syncthreads();                            // sync B: lpos ready for next scan
    }
}

extern "C" void kernel_launch(void* const* d_in, const int* in_sizes, int n_in,
                              void* d_out, int out_size, void* d_ws, size_t ws_size,
                              hipStream_t stream) {
    const float* pred = (const float*)d_in[0];
    const float* partial = (const float*)d_in[1];
    unsigned int* maxv = (unsigned int*)d_ws;
    unsigned int* cntv = maxv + NITER * B;
    float* out = (float*)d_out;

    hipMemsetAsync(d_ws, 0, 2 * NITER * B * sizeof(unsigned int), stream);

    void* args[] = {(void*)&pred, (void*)&partial, (void*)&maxv, (void*)&cntv, (void*)&out};
    hipLaunchCooperativeKernel((const void*)refine_all, dim3(NBLK), dim3(NTHR),
                               args, 0, stream);
}

// Round 7
// 320.055 us; speedup vs baseline: 1.0212x; 1.0212x over previous
//
#include <hip/hip_runtime.h>

#define B 8
#define N 8192
#define M 2048
#define NITER 4
#define BASE_ALPHA 0.1f

#define NTHR 1024              // 16 waves (4 waves/SIMD)
#define NPT 32                 // point-lanes per split
#define NSPLIT 32              // j-splits per block
#define JS (M / NSPLIT)        // 64 y's per split
#define PT 8                   // points per thread
#define PPB (NPT * PT)         // 256 points per block
#define NBLK (B * N / PPB)     // 256 blocks = 1/CU (unconditionally co-resident)
#define BPB (NBLK / B)         // 32 blocks per batch
#define CNT_TARGET (4 * BPB)   // 4 owner waves per block arrive independently

// ws: maxv uint[NITER*B] @0, cnt uint[NITER*B] @128 — 256 B, memsetAsync(0) per call.
// Tile PHYSICAL layout is transposed: logical y-index i = split*JS + j lives at
// tile[j*NSPLIT + split]. Pass-1 reads are half-wave-uniform (broadcast, 0-conflict,
// offset-immediate addressable); pass-2 per-lane bsplit reads spread over 8 bank
// groups (~4-way, 1.58x) instead of the 64-way same-bank pathology of the
// split-major layout (R6: 12.4M conflict cycles).

__device__ __forceinline__ unsigned int ord32(float t) {
    unsigned int u = __float_as_uint(t);
    return u ^ ((unsigned int)((int)u >> 31) | 0x80000000u);   // float order -> uint order
}
__device__ __forceinline__ float dec32(unsigned int h) {
    return __uint_as_float((h & 0x80000000u) ? (h ^ 0x80000000u) : ~h);
}

__global__ __launch_bounds__(NTHR, 4) void refine_all(const float* __restrict__ pred,
                                                      const float* __restrict__ partial,
                                                      unsigned int* __restrict__ maxv,
                                                      unsigned int* __restrict__ cnt,
                                                      float* __restrict__ out) {
    __shared__ float4 tile[M];                     // {-2y0,-2y1,-2y2,|y|^2}, transposed phys
    __shared__ unsigned long long lkeys[16][PPB];  // 32 KB: per-wave (min_t, split) keys
    __shared__ float4 lpos[PPB];                   // {x,y,z,|r|^2}
    __shared__ float mxbuf;
    __shared__ unsigned int flag;

    const int tid = threadIdx.x;
    const int b = blockIdx.x >> 5;                 // 32 blocks per batch
    const int gp0 = b * N + (blockIdx.x & 31) * PPB;

    // Build y-tile once. Writes are phys-contiguous (conflict-free); reads are
    // scattered-but-tiny (24 KB once, L2-resident). (-2y)*x bit-equal to (-2x)*y.
    const float* pa = partial + b * M * 3;
    for (int u = tid; u < M; u += NTHR) {
        int sp = u & (NSPLIT - 1);                 // phys u = jj*32 + sp
        int jj = u >> 5;
        int i = sp * JS + jj;                      // logical index
        float y0 = pa[i * 3 + 0], y1 = pa[i * 3 + 1], y2 = pa[i * 3 + 2];
        tile[u] = make_float4(-2.0f * y0, -2.0f * y1, -2.0f * y2,
                              y0 * y0 + y1 * y1 + y2 * y2);
    }
    if (tid == 0) flag = 0u;
    if (tid < PPB) {
        const float* pp = pred + (unsigned long long)(gp0 + tid) * 3;
        float x = pp[0], y = pp[1], z = pp[2];
        lpos[tid] = make_float4(x, y, z, x * x + y * y + z * z);
    }
    __syncthreads();

    const int split = tid >> 5;                    // 0..31 (uniform per half-wave)
    const int pt = tid & 31;
    const int wave = tid >> 6;                     // 0..15
    const float4* __restrict__ qs = tile + split;  // qs[j*32] = logical (split, j)

    for (int iter = 0; iter < NITER; ++iter) {
        // ---- pass 1: per-split MIN VALUE only (3.5 VALU/pair) ----
        float x0[PT], x1[PT], x2[PT];
        #pragma unroll
        for (int k = 0; k < PT; ++k) {
            float4 r = lpos[pt + k * NPT];
            x0[k] = r.x; x1[k] = r.y; x2[k] = r.z;
        }
        float vb[PT];
        #pragma unroll
        for (int k = 0; k < PT; ++k) vb[k] = 3.402823466e+38f;

        #pragma unroll 4
        for (int j = 0; j < JS; j += 2) {
            float4 q0 = qs[j * NSPLIT];
            float4 q1 = qs[(j + 1) * NSPLIT];
            #pragma unroll
            for (int k = 0; k < PT; ++k) {
                float t0 = fmaf(x0[k], q0.x, fmaf(x1[k], q0.y, fmaf(x2[k], q0.z, q0.w)));
                float t1 = fmaf(x0[k], q1.x, fmaf(x1[k], q1.y, fmaf(x2[k], q1.z, q1.w)));
                vb[k] = fminf(fminf(t0, t1), vb[k]);   // v_min3_f32
            }
        }

        // ---- merge (value, split) across the wave's two splits, write per-wave row ----
        #pragma unroll
        for (int k = 0; k < PT; ++k) {
            unsigned int hi = ord32(vb[k]);
            unsigned int lo = (unsigned int)split;
            unsigned int ohi = __shfl_xor(hi, 32), olo = __shfl_xor(lo, 32);
            if (ohi < hi || (ohi == hi && olo < lo)) { hi = ohi; lo = olo; }  // lex min
            if ((tid & 32) == 0)
                lkeys[wave][pt + k * NPT] = (((unsigned long long)hi) << 32) | lo;
        }
        __syncthreads();                            // sync A: lkeys ready

        // ---- owners (tid<256): reduce, barrier-arrive, pass-2 re-scan, update ----
        if (tid < PPB) {
            unsigned long long best = lkeys[0][tid];
            #pragma unroll
            for (int r = 1; r < 16; ++r) {
                unsigned long long c = lkeys[r][tid];
                if (c < best) best = c;
            }
            const int bsplit = (int)(unsigned int)(best & 0xFFFFFFFFull);
            const float tstar = dec32((unsigned int)(best >> 32));
            const float4 f4 = lpos[tid];
            const float md = sqrtf(fmaxf(f4.w + tstar, 0.0f));

            // arrive at per-batch barrier (4 owner waves arrive independently)
            float wm = md;
            for (int o = 32; o > 0; o >>= 1) wm = fmaxf(wm, __shfl_down(wm, o));
            if ((tid & 63) == 0) {
                __hip_atomic_fetch_max(&maxv[iter * B + b], __float_as_uint(wm),
                                       __ATOMIC_SEQ_CST, __HIP_MEMORY_SCOPE_AGENT);
                __hip_atomic_fetch_add(&cnt[iter * B + b], 1u,
                                       __ATOMIC_SEQ_CST, __HIP_MEMORY_SCOPE_AGENT);
            }

            // pass 2 (overlaps cross-block barrier latency): exact first-argmin in the
            // winning split — bit-identical fmaf chain; ~4-way banked in transposed tile.
            const float4* __restrict__ q2 = tile + bsplit;
            float bt = 3.402823466e+38f; int bj = 0;
            #pragma unroll 4
            for (int j = 0; j < JS; ++j) {
                float4 q = q2[j * NSPLIT];
                float t = fmaf(f4.x, q.x, fmaf(f4.y, q.y, fmaf(f4.z, q.z, q.w)));
                if (t < bt) { bt = t; bj = j; }     // strict < keeps earliest j
            }
            const float4 nr = tile[bj * NSPLIT + bsplit];

            // finish barrier: tid0 spins, broadcasts via LDS flag
            if (tid == 0) {
                unsigned int* cv = &cnt[iter * B + b];
                while (__hip_atomic_load(cv, __ATOMIC_ACQUIRE, __HIP_MEMORY_SCOPE_AGENT)
                       < CNT_TARGET)
                    __builtin_amdgcn_s_sleep(1);
                unsigned int mu = __hip_atomic_load(&maxv[iter * B + b],
                                                    __ATOMIC_ACQUIRE, __HIP_MEMORY_SCOPE_AGENT);
                mxbuf = __uint_as_float(mu);
                __hip_atomic_store(&flag, (unsigned int)(iter + 1),
                                   __ATOMIC_RELEASE, __HIP_MEMORY_SCOPE_WORKGROUP);
            }
            if (wave != 0) {
                while (__hip_atomic_load(&flag, __ATOMIC_ACQUIRE,
                                         __HIP_MEMORY_SCOPE_WORKGROUP) < (unsigned int)(iter + 1))
                    __builtin_amdgcn_s_sleep(1);
            }
            const float mx = mxbuf;                 // wave0: same-wave DS order; others: after acquire

            const float inv = 1.0f / (mx + 1e-6f);
            const float alpha = BASE_ALPHA * (2.0f - md * inv);
            const float ny0 = -0.5f * nr.x, ny1 = -0.5f * nr.y, ny2 = -0.5f * nr.z;  // exact
            const float rx = fmaf(alpha, ny0 - f4.x, f4.x);
            const float ry = fmaf(alpha, ny1 - f4.y, f4.y);
            const float rz = fmaf(alpha, ny2 - f4.z, f4.z);
            if (iter == NITER - 1) {
                float* po = out + (unsigned long long)(gp0 + tid) * 3;
                po[0] = rx; po[1] = ry; po[2] = rz;
            } else {
                lpos[tid] = make_float4(rx, ry, rz, rx * rx + ry * ry + rz * rz);
            }
        }
        __syncthreads();                            // sync B: lpos ready for next scan
    }
}

extern "C" void kernel_launch(void* const* d_in, const int* in_sizes, int n_in,
                              void* d_out, int out_size, void* d_ws, size_t ws_size,
                              hipStream_t stream) {
    const float* pred = (const float*)d_in[0];
    const float* partial = (const float*)d_in[1];
    unsigned int* maxv = (unsigned int*)d_ws;
    unsigned int* cntv = maxv + NITER * B;
    float* out = (float*)d_out;

    hipMemsetAsync(d_ws, 0, 2 * NITER * B * sizeof(unsigned int), stream);

    void* args[] = {(void*)&pred, (void*)&partial, (void*)&maxv, (void*)&cntv, (void*)&out};
    hipLaunchCooperativeKernel((const void*)refine_all, dim3(NBLK), dim3(NTHR),
                               args, 0, stream);
}